// Round 5
// baseline (4610.548 us; speedup 1.0000x reference)
//
#include <hip/hip_runtime.h>
#include <hip/hip_bf16.h>

// LSTM decoder: L=512, B=64, A=256, I=256, H=512, 4H=2048.
// R5 = R2's exact handshake (single counter + fetch_add + uniform poll +
// acquire fence) with streamlined interior:
//  - swapped MFMA (A=weights, D-rows permuted so r4=gate) -> cell update in regs
//  - act-part MFMAs hoisted before the poll (run in the spin shadow)

#define NWG     64
#define LSTEPS  512
#define BATCH   64
#define HDIM    512
#define ADIM    256
#define GDIM    2048
#define KTOT    768
#define LBH     (LSTEPS*BATCH*HDIM)
#define HWORDS  (BATCH*256)          // u32 words per h buffer

typedef __attribute__((ext_vector_type(4))) float f32x4;
typedef __attribute__((ext_vector_type(8))) short s16x8;

__device__ __forceinline__ unsigned short f2bf(float f){
  unsigned u = __builtin_bit_cast(unsigned, f);
  u = (u + 0x7fffu + ((u >> 16) & 1u)) >> 16;   // round-to-nearest-even
  return (unsigned short)u;
}
__device__ __forceinline__ float sigm(float x){ return 1.f / (1.f + __expf(-x)); }
__device__ __forceinline__ float ftanh(float x){ return 1.f - 2.f / (__expf(2.f*x) + 1.f); }

// ---------------- precompute kernels ----------------

__global__ void cvt_act(const float* __restrict__ in, unsigned short* __restrict__ ob, int n8){
  int i = blockIdx.x * blockDim.x + threadIdx.x;
  if (i >= n8) return;
  const float4* p = (const float4*)in + (size_t)i * 2;
  float4 a = p[0], b = p[1];
  int4 o;
  o.x = (int)((unsigned)f2bf(a.x) | ((unsigned)f2bf(a.y) << 16));
  o.y = (int)((unsigned)f2bf(a.z) | ((unsigned)f2bf(a.w) << 16));
  o.z = (int)((unsigned)f2bf(b.x) | ((unsigned)f2bf(b.y) << 16));
  o.w = (int)((unsigned)f2bf(b.z) | ((unsigned)f2bf(b.w) << 16));
  ((int4*)ob)[i] = o;
}

__global__ void static_gates_k(const float* __restrict__ inp, const float* __restrict__ Wih,
                               const float* __restrict__ bih, const float* __restrict__ bhh,
                               float* __restrict__ statg){
  int g = blockIdx.x;
  int b = threadIdx.x;
  const float4* w = (const float4*)(Wih + (size_t)g * 512);
  const float4* x = (const float4*)(inp + (size_t)b * 256);
  float acc = 0.f;
#pragma unroll 8
  for (int i = 0; i < 64; ++i){
    float4 wv = w[i], xv = x[i];
    acc += wv.x*xv.x + wv.y*xv.y + wv.z*xv.z + wv.w*xv.w;
  }
  statg[b*GDIM + g] = acc + bih[g] + bhh[g];
}

__global__ void init_h(const float* __restrict__ h0, unsigned int* __restrict__ hbuf32){
  int i = blockIdx.x * blockDim.x + threadIdx.x;
  if (i < HWORDS){
    unsigned lo = f2bf(h0[2*i]), hi = f2bf(h0[2*i+1]);
    hbuf32[HWORDS + i] = lo | (hi << 16);
  }
}

// ---------------- persistent LSTM kernel ----------------

__global__ __launch_bounds__(256, 1) void lstm_persistent(
    const unsigned short* __restrict__ act_bf,   // [L][B][A] bf16
    const float*          __restrict__ statg,    // [B][4H]
    const float*          __restrict__ Whh,      // [4H][H]
    const float*          __restrict__ Wih,      // [4H][I+A]
    const float*          __restrict__ c0,       // [B][H]
    float*                __restrict__ out,      // hs, h_n, c_n
    unsigned int*         __restrict__ hbuf32,   // [2][B][256] packed bf16x2
    unsigned int*         __restrict__ done)     // [L] arrival counters
{
  __shared__ short Albuf[64 * KTOT];   // [batch 64][K 768] bf16, XOR-swizzled
  __shared__ float hb[64 * 9];         // h bounce, padded stride 9

  const int tid   = threadIdx.x;
  const int wgk   = blockIdx.x;        // owns hidden units [8*wgk, 8*wgk+8)
  const int lane  = tid & 63;
  const int wid   = tid >> 6;
  const int m     = wid & 1;           // gate-row 16-tile
  const int npair = wid >> 1;          // batch 32-group (2 n-tiles)
  const int kgrp  = (lane >> 4) * 8;

  // ---- A-frags (weights) in regs. D-row permutation: row_in_tile = u_off*4+g4,
  //      grow = g4*512 + wgk*8 + m*4 + u_off  (verified correct in R3).
  const int rit  = lane & 15;
  const int grow = (rit & 3)*512 + wgk*8 + m*4 + (rit >> 2);
  s16x8 aw[24];
#pragma unroll
  for (int kk = 0; kk < 16; ++kk){                 // K 0..511 : W_hh
    s16x8 v;
    const int kb = kk*32 + kgrp;
#pragma unroll
    for (int e = 0; e < 8; ++e)
      v[e] = (short)f2bf(Whh[(size_t)grow*512 + kb + e]);
    aw[kk] = v;
  }
#pragma unroll
  for (int kk = 16; kk < 24; ++kk){                // K 512..767 : W_a (cols 256..511)
    s16x8 v;
    const int kb = kk*32 + kgrp;
#pragma unroll
    for (int e = 0; e < 8; ++e)
      v[e] = (short)f2bf(Wih[(size_t)grow*512 + (kb - 256) + e]);
    aw[kk] = v;
  }

  // ---- swapped-layout state mapping (C/D: col=lane&15 -> batch, row -> unit,gate) ----
  const int bA   = (npair*2)*16 + (lane & 15);     // batch for n-tile 0
  const int bB   = bA + 16;                        // batch for n-tile 1
  const int j    = wgk*8 + m*4 + (lane >> 4);      // hidden unit
  const int uloc = m*4 + (lane >> 4);              // unit within WG (0..7)
  float stat[2][4], cr[2];
#pragma unroll
  for (int g4 = 0; g4 < 4; ++g4){
    stat[0][g4] = statg[bA*GDIM + g4*512 + j];
    stat[1][g4] = statg[bB*GDIM + g4*512 + j];
  }
  cr[0] = c0[bA*HDIM + j];
  cr[1] = c0[bB*HDIM + j];

  // R2-mapping for publish / hs-out
  const int b_cu = tid >> 2;           // 0..63
  const int u0   = (tid & 3) * 2;      // 0,2,4,6
  const int j0   = wgk*8 + u0;

  // LDS row bases for B-frag reads
  const int r0  = bA;
  const int sw0 = (r0 & 7) * 8;

  // ---- prologue: stage act(0) ----
  {
    const unsigned short* asrc = act_bf;
#pragma unroll
    for (int it = 0; it < 8; ++it){
      const int idx = it*256 + tid;
      const int r = idx >> 5, ch = idx & 31;
      int4 v = *(const int4*)(asrc + r*ADIM + ch*8);
      *(int4*)(&Albuf[r*KTOT + 512 + ((ch ^ (r & 7)) * 8)]) = v;
    }
  }

  for (int t = 0; t < LSTEPS; ++t){
    __syncthreads();   // B0: act region staged (prologue or prev-iter prestage)

    // ---- act-part MFMAs (K 512..767) -- in the spin shadow ----
    f32x4 acc0 = {0.f,0.f,0.f,0.f}, acc1 = {0.f,0.f,0.f,0.f};
    {
      const short* arow0 = &Albuf[r0 * KTOT];
      const short* arow1 = &Albuf[(r0+16) * KTOT];
#pragma unroll
      for (int kk = 16; kk < 24; ++kk){
        const int col = (kk*32 + kgrp) ^ sw0;
        s16x8 b0 = *(const s16x8*)(arow0 + col);
        s16x8 b1 = *(const s16x8*)(arow1 + col);
        acc0 = __builtin_amdgcn_mfma_f32_16x16x32_bf16(aw[kk], b0, acc0, 0, 0, 0);
        acc1 = __builtin_amdgcn_mfma_f32_16x16x32_bf16(aw[kk], b1, acc1, 0, 0, 0);
      }
    }

    // ---- wait for h_{t-1}: R2's exact uniform poll + single fence ----
    if (t > 0){
      while (__hip_atomic_load(&done[t-1], __ATOMIC_RELAXED, __HIP_MEMORY_SCOPE_AGENT) < NWG){}
      __builtin_amdgcn_fence(__ATOMIC_ACQUIRE, "agent");
    }
    // ---- stage h (cached, pipelined int4 loads) ----
    {
      const int4* hp = (const int4*)(hbuf32 + ((t+1) & 1) * HWORDS);
#pragma unroll
      for (int it = 0; it < 16; ++it){
        const int idx = it*256 + tid;
        const int r = idx >> 6, ch = idx & 63;
        int4 v = hp[r*64 + ch];
        *(int4*)(&Albuf[r*KTOT + ((ch ^ (r & 7)) * 8)]) = v;
      }
    }
    __syncthreads();   // B1: h staged

    // ---- h-part MFMAs (K 0..511) ----
    {
      const short* arow0 = &Albuf[r0 * KTOT];
      const short* arow1 = &Albuf[(r0+16) * KTOT];
#pragma unroll
      for (int kk = 0; kk < 16; ++kk){
        const int col = (kk*32 + kgrp) ^ sw0;
        s16x8 b0 = *(const s16x8*)(arow0 + col);
        s16x8 b1 = *(const s16x8*)(arow1 + col);
        acc0 = __builtin_amdgcn_mfma_f32_16x16x32_bf16(aw[kk], b0, acc0, 0, 0, 0);
        acc1 = __builtin_amdgcn_mfma_f32_16x16x32_bf16(aw[kk], b1, acc1, 0, 0, 0);
      }
    }

    // ---- cell update in regs (r4 = gate index) ----
    float hv[2];
    {
      float iv = sigm(acc0[0] + stat[0][0]);
      float fv = sigm(acc0[1] + stat[0][1]);
      float gv = ftanh(acc0[2] + stat[0][2]);
      float ov = sigm(acc0[3] + stat[0][3]);
      float c = fv * cr[0] + iv * gv;
      cr[0] = c; hv[0] = ov * ftanh(c);
      iv = sigm(acc1[0] + stat[1][0]);
      fv = sigm(acc1[1] + stat[1][1]);
      gv = ftanh(acc1[2] + stat[1][2]);
      ov = sigm(acc1[3] + stat[1][3]);
      c = fv * cr[1] + iv * gv;
      cr[1] = c; hv[1] = ov * ftanh(c);
    }
    hb[bA*9 + uloc] = hv[0];
    hb[bB*9 + uloc] = hv[1];
    __syncthreads();   // B2: hb complete

    // ---- hs-out + publish (R2's exact mapping and traffic) ----
    {
      float h0v = hb[b_cu*9 + u0], h1v = hb[b_cu*9 + u0 + 1];
      float2 h2o; h2o.x = h0v; h2o.y = h1v;
      *(float2*)&out[((size_t)t*BATCH + b_cu)*HDIM + j0] = h2o;
      unsigned pk = (unsigned)f2bf(h0v) | ((unsigned)f2bf(h1v) << 16);
      __hip_atomic_store(&hbuf32[(t & 1)*HWORDS + b_cu*256 + (j0 >> 1)], pk,
                         __ATOMIC_RELAXED, __HIP_MEMORY_SCOPE_AGENT);
    }
    __syncthreads();   // B3: drain (vmcnt0) -> publishes at coherence point
    if (tid == 0)
      __hip_atomic_fetch_add(&done[t], 1u, __ATOMIC_RELAXED, __HIP_MEMORY_SCOPE_AGENT);

    // ---- off critical path: finals / next act prestage ----
    if (t == LSTEPS-1){
      out[LBH + bA*HDIM + j] = hv[0];
      out[LBH + bB*HDIM + j] = hv[1];
      out[LBH + BATCH*HDIM + bA*HDIM + j] = cr[0];
      out[LBH + BATCH*HDIM + bB*HDIM + j] = cr[1];
    } else {
      const unsigned short* asrc = act_bf + (size_t)(t+1) * (BATCH*ADIM);
#pragma unroll
      for (int it = 0; it < 8; ++it){
        const int idx = it*256 + tid;
        const int r = idx >> 5, ch = idx & 31;
        int4 v = *(const int4*)(asrc + r*ADIM + ch*8);
        *(int4*)(&Albuf[r*KTOT + 512 + ((ch ^ (r & 7)) * 8)]) = v;
      }
    }
  }
}

// ---------------- launch ----------------

extern "C" void kernel_launch(void* const* d_in, const int* in_sizes, int n_in,
                              void* d_out, int out_size, void* d_ws, size_t ws_size,
                              hipStream_t stream){
  const float* act = (const float*)d_in[0];
  const float* inp = (const float*)d_in[1];
  const float* h0  = (const float*)d_in[2];
  const float* c0  = (const float*)d_in[3];
  const float* Wih = (const float*)d_in[4];
  const float* Whh = (const float*)d_in[5];
  const float* bih = (const float*)d_in[6];
  const float* bhh = (const float*)d_in[7];
  float* out = (float*)d_out;

  char* ws = (char*)d_ws;
  unsigned short* act_bf = (unsigned short*)ws;                          // 16 MiB
  unsigned int*   hbuf32 = (unsigned int*)(ws + 16777216);               // 128 KiB
  float*          statg  = (float*)(ws + 16777216 + 131072);             // 512 KiB
  unsigned int*   done   = (unsigned int*)(ws + 16777216 + 131072 + 524288); // 2 KiB

  hipMemsetAsync(done, 0, LSTEPS * sizeof(unsigned int), stream);
  cvt_act<<<4096, 256, 0, stream>>>(act, act_bf, (LSTEPS*BATCH*ADIM)/8);
  static_gates_k<<<GDIM, 64, 0, stream>>>(inp, Wih, bih, bhh, statg);
  init_h<<<64, 256, 0, stream>>>(h0, hbuf32);
  lstm_persistent<<<NWG, 256, 0, stream>>>(act_bf, statg, Whh, Wih, c0, out, hbuf32, done);
}

// Round 6
// 2780.350 us; speedup vs baseline: 1.6583x; 1.6583x over previous
//
#include <hip/hip_runtime.h>
#include <hip/hip_bf16.h>

// LSTM decoder: L=512, B=64, A=256, I=256, H=512, 4H=2048.
// R6 = R2's exact structure/ordering, rescaled to 32 WGs x 512 threads
// (each WG owns 16 hidden units = 64 gate rows). Single variable vs R2:
// halves the arrival chain (32 fetch_adds) and the h-exchange traffic.

#define NWG     32
#define THREADS 512
#define LSTEPS  512
#define BATCH   64
#define HDIM    512
#define ADIM    256
#define GDIM    2048
#define KTOT    768
#define LBH     (LSTEPS*BATCH*HDIM)
#define HWORDS  (BATCH*256)          // u32 words per h buffer

typedef __attribute__((ext_vector_type(4))) float f32x4;
typedef __attribute__((ext_vector_type(8))) short s16x8;

__device__ __forceinline__ unsigned short f2bf(float f){
  unsigned u = __builtin_bit_cast(unsigned, f);
  u = (u + 0x7fffu + ((u >> 16) & 1u)) >> 16;   // round-to-nearest-even
  return (unsigned short)u;
}
__device__ __forceinline__ float sigm(float x){ return 1.f / (1.f + __expf(-x)); }
__device__ __forceinline__ float ftanh(float x){ return 1.f - 2.f / (__expf(2.f*x) + 1.f); }

// ---------------- precompute kernels ----------------

__global__ void cvt_act(const float* __restrict__ in, unsigned short* __restrict__ ob, int n8){
  int i = blockIdx.x * blockDim.x + threadIdx.x;
  if (i >= n8) return;
  const float4* p = (const float4*)in + (size_t)i * 2;
  float4 a = p[0], b = p[1];
  int4 o;
  o.x = (int)((unsigned)f2bf(a.x) | ((unsigned)f2bf(a.y) << 16));
  o.y = (int)((unsigned)f2bf(a.z) | ((unsigned)f2bf(a.w) << 16));
  o.z = (int)((unsigned)f2bf(b.x) | ((unsigned)f2bf(b.y) << 16));
  o.w = (int)((unsigned)f2bf(b.z) | ((unsigned)f2bf(b.w) << 16));
  ((int4*)ob)[i] = o;
}

__global__ void static_gates_k(const float* __restrict__ inp, const float* __restrict__ Wih,
                               const float* __restrict__ bih, const float* __restrict__ bhh,
                               float* __restrict__ statg){
  int g = blockIdx.x;
  int b = threadIdx.x;
  const float4* w = (const float4*)(Wih + (size_t)g * 512);
  const float4* x = (const float4*)(inp + (size_t)b * 256);
  float acc = 0.f;
#pragma unroll 8
  for (int i = 0; i < 64; ++i){
    float4 wv = w[i], xv = x[i];
    acc += wv.x*xv.x + wv.y*xv.y + wv.z*xv.z + wv.w*xv.w;
  }
  statg[b*GDIM + g] = acc + bih[g] + bhh[g];
}

__global__ void init_h(const float* __restrict__ h0, unsigned int* __restrict__ hbuf32){
  int i = blockIdx.x * blockDim.x + threadIdx.x;
  if (i < HWORDS){
    unsigned lo = f2bf(h0[2*i]), hi = f2bf(h0[2*i+1]);
    hbuf32[HWORDS + i] = lo | (hi << 16);
  }
}

// ---------------- persistent LSTM kernel ----------------

__global__ __launch_bounds__(512, 1) void lstm_persistent(
    const unsigned short* __restrict__ act_bf,   // [L][B][A] bf16
    const float*          __restrict__ statg,    // [B][4H]
    const float*          __restrict__ Whh,      // [4H][H]
    const float*          __restrict__ Wih,      // [4H][I+A]
    const float*          __restrict__ c0,       // [B][H]
    float*                __restrict__ out,      // hs, h_n, c_n
    unsigned int*         __restrict__ hbuf32,   // [2][B][256] packed bf16x2
    unsigned int*         __restrict__ done)     // [L] arrival counters
{
  __shared__ short Albuf[64 * KTOT];   // [batch 64][K 768] bf16, XOR-swizzled
  __shared__ float gbuf[64 * 68];      // gate staging: 64 batch x 64 cols, pad 4

  const int tid  = threadIdx.x;
  const int wgk  = blockIdx.x;         // owns hidden units [16*wgk, 16*wgk+16)
  const int lane = tid & 63;
  const int wid  = tid >> 6;           // 0..7
  const int wm   = wid & 1;            // batch half (2 m-tiles each)
  const int wn   = wid >> 1;           // n-tile 0..3 (16 gate cols each)
  const int kgrp = (lane >> 4) * 8;

  // ---- B fragments (weights) in registers ----
  // local col cl in [0,64): gate g4 = cl>>4, unit u = cl&15
  const int cl   = wn*16 + (lane & 15);
  const int grow = (cl >> 4)*512 + wgk*16 + (cl & 15);   // global gate row
  s16x8 bw[24];
#pragma unroll
  for (int kk = 0; kk < 16; ++kk){                     // K 0..511 : W_hh
    s16x8 v;
    const int kb = kk*32 + kgrp;
#pragma unroll
    for (int e = 0; e < 8; ++e)
      v[e] = (short)f2bf(Whh[(size_t)grow*512 + kb + e]);
    bw[kk] = v;
  }
#pragma unroll
  for (int kk = 16; kk < 24; ++kk){                    // K 512..767 : W_a
    s16x8 v;
    const int kb = kk*32 + kgrp;
#pragma unroll
    for (int e = 0; e < 8; ++e)
      v[e] = (short)f2bf(Wih[(size_t)grow*512 + (kb - 256) + e]);
    bw[kk] = v;
  }

  // ---- cell-update mapping: thread -> (batch b_cu, units j0, j0+1) ----
  const int b_cu = tid >> 3;           // 0..63
  const int u0   = (tid & 7) * 2;      // 0,2,..,14
  const int j0   = wgk*16 + u0;
  float stat2[2][4], cr[2];
#pragma unroll
  for (int pi = 0; pi < 2; ++pi){
    const int j = j0 + pi;
#pragma unroll
    for (int g4 = 0; g4 < 4; ++g4)
      stat2[pi][g4] = statg[b_cu*GDIM + g4*512 + j];
    cr[pi] = c0[b_cu*HDIM + j];
  }

  for (int t = 0; t < LSTEPS; ++t){
    // ---- stage act(t) (independent of h -> before the wait) ----
    {
      const unsigned short* asrc = act_bf + (size_t)t * (BATCH*ADIM);
#pragma unroll
      for (int it = 0; it < 4; ++it){
        const int idx = it*THREADS + tid;
        const int r = idx >> 5, ch = idx & 31;
        int4 v = *(const int4*)(asrc + r*ADIM + ch*8);
        *(int4*)(&Albuf[r*KTOT + 512 + ((ch ^ (r & 7)) * 8)]) = v;
      }
    }
    // ---- wait for h_{t-1}: uniform poll + single acquire fence ----
    if (t > 0){
      while (__hip_atomic_load(&done[t-1], __ATOMIC_RELAXED, __HIP_MEMORY_SCOPE_AGENT) < NWG){}
      __builtin_amdgcn_fence(__ATOMIC_ACQUIRE, "agent");
    }
    // ---- stage h (cached, pipelined int4 loads) ----
    {
      const int4* hp = (const int4*)(hbuf32 + ((t+1) & 1) * HWORDS);
#pragma unroll
      for (int it = 0; it < 8; ++it){
        const int idx = it*THREADS + tid;
        const int r = idx >> 6, ch = idx & 63;
        int4 v = hp[r*64 + ch];
        *(int4*)(&Albuf[r*KTOT + ((ch ^ (r & 7)) * 8)]) = v;
      }
    }
    __syncthreads();   // B1: tile staged

    // ---- MFMA: D[64 batch][64 gate cols] over K=768 ----
    f32x4 acc[2];
#pragma unroll
    for (int m = 0; m < 2; ++m){
      f32x4 a = {0.f, 0.f, 0.f, 0.f};
      const int r  = wm*32 + m*16 + (lane & 15);
      const short* arow = &Albuf[r * KTOT];
      const int sw = (r & 7) * 8;
#pragma unroll
      for (int kk = 0; kk < 24; ++kk){
        const int col = (kk*32 + kgrp) ^ sw;
        s16x8 af = *(const s16x8*)(arow + col);
        a = __builtin_amdgcn_mfma_f32_16x16x32_bf16(af, bw[kk], a, 0, 0, 0);
      }
      acc[m] = a;
    }
    // scatter gates to LDS (C/D layout: col=lane&15, row=(lane>>4)*4+reg)
#pragma unroll
    for (int m = 0; m < 2; ++m){
      const int base_b = wm*32 + m*16 + ((lane >> 4) * 4);
#pragma unroll
      for (int r4 = 0; r4 < 4; ++r4)
        gbuf[(base_b + r4)*68 + cl] = acc[m][r4];
    }
    __syncthreads();   // B2: gbuf complete

    // ---- elementwise LSTM cell + hs-out + publish (all pre-drain) ----
    float hv[2];
    {
      const float* gb = &gbuf[b_cu*68];
#pragma unroll
      for (int pi = 0; pi < 2; ++pi){
        const int u = u0 + pi;
        float iv = gb[u]      + stat2[pi][0];
        float fv = gb[16 + u] + stat2[pi][1];
        float gv = gb[32 + u] + stat2[pi][2];
        float ov = gb[48 + u] + stat2[pi][3];
        iv = sigm(iv); fv = sigm(fv); gv = ftanh(gv); ov = sigm(ov);
        float c = fv * cr[pi] + iv * gv;
        cr[pi] = c;
        hv[pi] = ov * ftanh(c);
      }
      float2 h2o; h2o.x = hv[0]; h2o.y = hv[1];
      *(float2*)&out[((size_t)t*BATCH + b_cu)*HDIM + j0] = h2o;
      unsigned pk = (unsigned)f2bf(hv[0]) | ((unsigned)f2bf(hv[1]) << 16);
      __hip_atomic_store(&hbuf32[(t & 1)*HWORDS + b_cu*256 + (j0 >> 1)], pk,
                         __ATOMIC_RELAXED, __HIP_MEMORY_SCOPE_AGENT);
      if (t == LSTEPS-1){
        float2 c2o; c2o.x = cr[0]; c2o.y = cr[1];
        *(float2*)&out[LBH + b_cu*HDIM + j0] = h2o;
        *(float2*)&out[LBH + BATCH*HDIM + b_cu*HDIM + j0] = c2o;
      }
    }
    // B3: vmcnt(0) drain at barrier -> all publishes at coherence point
    __syncthreads();
    if (tid == 0)
      __hip_atomic_fetch_add(&done[t], 1u, __ATOMIC_RELAXED, __HIP_MEMORY_SCOPE_AGENT);
  }
}

// ---------------- launch ----------------

extern "C" void kernel_launch(void* const* d_in, const int* in_sizes, int n_in,
                              void* d_out, int out_size, void* d_ws, size_t ws_size,
                              hipStream_t stream){
  const float* act = (const float*)d_in[0];
  const float* inp = (const float*)d_in[1];
  const float* h0  = (const float*)d_in[2];
  const float* c0  = (const float*)d_in[3];
  const float* Wih = (const float*)d_in[4];
  const float* Whh = (const float*)d_in[5];
  const float* bih = (const float*)d_in[6];
  const float* bhh = (const float*)d_in[7];
  float* out = (float*)d_out;

  char* ws = (char*)d_ws;
  unsigned short* act_bf = (unsigned short*)ws;                          // 16 MiB
  unsigned int*   hbuf32 = (unsigned int*)(ws + 16777216);               // 128 KiB
  float*          statg  = (float*)(ws + 16777216 + 131072);             // 512 KiB
  unsigned int*   done   = (unsigned int*)(ws + 16777216 + 131072 + 524288); // 2 KiB

  hipMemsetAsync(done, 0, LSTEPS * sizeof(unsigned int), stream);
  cvt_act<<<4096, 256, 0, stream>>>(act, act_bf, (LSTEPS*BATCH*ADIM)/8);
  static_gates_k<<<GDIM, 64, 0, stream>>>(inp, Wih, bih, bhh, statg);
  init_h<<<64, 256, 0, stream>>>(h0, hbuf32);
  lstm_persistent<<<NWG, THREADS, 0, stream>>>(act_bf, statg, Whh, Wih, c0, out, hbuf32, done);
}